// Round 2
// baseline (177.961 us; speedup 1.0000x reference)
//
#include <hip/hip_runtime.h>
#include <cstdint>
#include <cstddef>

typedef _Float16 half_t;
typedef _Float16 half8 __attribute__((ext_vector_type(8)));
typedef float floatx4 __attribute__((ext_vector_type(4)));

#define E_ 8
#define D_ 512
#define H_ 2048
#define NTOK 1024
#define NP 2048          // NTOK * top_k
#define TM 64            // GEMM M-tile (rows)
#define MAX_TILES 40     // 2048/64 + 8 experts

__device__ __forceinline__ float gelu_f(float x) {
    return 0.5f * x * (1.0f + erff(x * 0.7071067811865476f));
}

// async global->LDS, 16 bytes per lane; LDS dest is wave-uniform base + lane*16
__device__ __forceinline__ void gload_lds16(const half_t* g, half_t* l) {
    __builtin_amdgcn_global_load_lds(
        (__attribute__((address_space(1))) void*)(g),
        (__attribute__((address_space(3))) void*)(l),
        16, 0, 0);
}

// ---------------- gate: logits only (no atomics) ----------------
__global__ __launch_bounds__(256) void gate_kernel(
        const float* __restrict__ inp, const float* __restrict__ gate_w,
        const float* __restrict__ gate_b, float* __restrict__ logits) {
    int n = blockIdx.x * 4 + (threadIdx.x >> 6);
    int lane = threadIdx.x & 63;
    const floatx4* xr = (const floatx4*)(inp + (size_t)n * D_);
    floatx4 x0 = xr[lane * 2], x1 = xr[lane * 2 + 1];
    #pragma unroll
    for (int e = 0; e < E_; e++) {
        const floatx4* gr = (const floatx4*)(gate_w + (size_t)e * D_);
        floatx4 g0 = gr[lane * 2], g1 = gr[lane * 2 + 1];
        float p = x0[0]*g0[0] + x0[1]*g0[1] + x0[2]*g0[2] + x0[3]*g0[3]
                + x1[0]*g1[0] + x1[1]*g1[1] + x1[2]*g1[2] + x1[3]*g1[3];
        #pragma unroll
        for (int m = 1; m < 64; m <<= 1) p += __shfl_xor(p, m);
        if (lane == 0) logits[(size_t)n * E_ + e] = p + gate_b[e];
    }
}

// ---------------- plan: single block does top2/softmax/hist/offsets/tiles ----------------
__global__ __launch_bounds__(256) void plan_kernel(
        const float* __restrict__ logits, float* __restrict__ score,
        int* __restrict__ idx, int* __restrict__ pos_of_pair,
        int* __restrict__ tile_e, int* __restrict__ tile_row0,
        int* __restrict__ tile_cnt, int* __restrict__ ntiles) {
    __shared__ int cnt_s[E_], off_s[E_ + 1], cur_s[E_];
    int tid = threadIdx.x;
    if (tid < E_) { cnt_s[tid] = 0; cur_s[tid] = 0; }
    __syncthreads();
    int my_e[4][2];
    #pragma unroll
    for (int i = 0; i < 4; i++) {
        int n = tid + i * 256;
        float l[E_];
        #pragma unroll
        for (int e = 0; e < E_; e++) l[e] = logits[(size_t)n * E_ + e];
        int e0 = 0; float v0 = l[0];
        #pragma unroll
        for (int e = 1; e < E_; e++) if (l[e] > v0) { v0 = l[e]; e0 = e; }
        int e1 = -1; float v1 = -3.4e38f;
        #pragma unroll
        for (int e = 0; e < E_; e++) if (e != e0 && l[e] > v1) { v1 = l[e]; e1 = e; }
        float s1 = expf(v1 - v0);
        float den = 1.0f + s1;
        score[2 * n]     = 1.0f / den;
        score[2 * n + 1] = s1 / den;
        idx[2 * n]     = e0;
        idx[2 * n + 1] = e1;
        atomicAdd(&cnt_s[e0], 1);
        atomicAdd(&cnt_s[e1], 1);
        my_e[i][0] = e0; my_e[i][1] = e1;
    }
    __syncthreads();
    if (tid == 0) {
        int o = 0;
        #pragma unroll
        for (int e = 0; e < E_; e++) { off_s[e] = o; o += cnt_s[e]; }
        off_s[E_] = o;
        int t = 0;
        for (int e = 0; e < E_; e++) {
            int c = cnt_s[e];
            int nt = (c + TM - 1) / TM;
            for (int i = 0; i < nt; i++) {
                tile_e[t] = e;
                tile_row0[t] = off_s[e] + i * TM;
                int rem = c - i * TM;
                tile_cnt[t] = rem < TM ? rem : TM;
                t++;
            }
        }
        ntiles[0] = t;
    }
    __syncthreads();
    #pragma unroll
    for (int i = 0; i < 4; i++) {
        #pragma unroll
        for (int k = 0; k < 2; k++) {
            int p = (tid + i * 256) * 2 + k;
            int e = my_e[i][k];
            int r = atomicAdd(&cur_s[e], 1);
            pos_of_pair[p] = off_s[e] + r;
        }
    }
}

// ---------------- scatter: copy token rows to f16 at grouped positions ----------------
__global__ __launch_bounds__(256) void scatter_kernel(
        const float* __restrict__ inp, const int* __restrict__ pos_of_pair,
        half_t* __restrict__ Xg) {
    int p = blockIdx.x * 4 + (threadIdx.x >> 6);
    int lane = threadIdx.x & 63;
    int pos = pos_of_pair[p];
    int n = p >> 1;
    const floatx4* src = (const floatx4*)(inp + (size_t)n * D_);
    floatx4 f0 = src[lane * 2], f1 = src[lane * 2 + 1];
    half8 h = { (half_t)f0[0], (half_t)f0[1], (half_t)f0[2], (half_t)f0[3],
                (half_t)f1[0], (half_t)f1[1], (half_t)f1[2], (half_t)f1[3] };
    *(half8*)(Xg + (size_t)pos * D_ + lane * 8) = h;
}

// ---------------- GEMM1: Y1 = gelu(Xg @ W1[e]^T + b1[e]) ----------------
// 64x128 tile, BK=64, double-buffered LDS, XOR-swizzled granules (2-way reads),
// A staged via global_load_lds with pre-swizzled source, B reg-staged f32->f16.
__global__ __launch_bounds__(256) void gemm1_kernel(
        const half_t* __restrict__ Xg, const float* __restrict__ w1,
        const float* __restrict__ b1,
        const int* __restrict__ tile_e, const int* __restrict__ tile_row0,
        const int* __restrict__ tile_cnt, const int* __restrict__ ntiles,
        half_t* __restrict__ Y1) {
    __shared__ half_t As[2][64 * 64];    // 2 x 8 KB
    __shared__ half_t Bs[2][128 * 64];   // 2 x 16 KB
    int t = blockIdx.x;
    if (t >= ntiles[0]) return;
    int e = tile_e[t], row0 = tile_row0[t], cnt = tile_cnt[t];
    int colbase = blockIdx.y * 128;
    int tid = threadIdx.x;
    int wave = tid >> 6, lane = tid & 63;
    int quad = lane >> 4, l16 = lane & 15;
    int wm = (wave & 1) * 32, wn = (wave >> 1) * 64;
    int xm = l16 & 7;                    // read-side XOR mask (row&7)

    // granule coords: each 16B granule = 8 halfs; tile row stride = 8 granules
    int gr = tid >> 3, gc = tid & 7;
    int gsw = gc ^ (gr & 7);             // swizzle (row&7 invariant under +32)

    // A source pre-swizzled (LDS dest linear, required by global_load_lds)
    const half_t* Ag0 = Xg + (size_t)(row0 + gr) * D_ + gsw * 8;
    const half_t* Ag1 = Ag0 + 32 * D_;
    // B natural source; swizzle applied on ds_write
    const float* Bg = w1 + ((size_t)e * H_ + colbase + gr) * D_ + gc * 8;
    int bslot = gr * 64 + gsw * 8;       // halfs offset of granule (gr, swz)

    floatx4 br0[4], br1[4];

    #define STAGEA1(buf, k0) do { \
        gload_lds16(Ag0 + (k0), &As[buf][(size_t)tid * 8]); \
        gload_lds16(Ag1 + (k0), &As[buf][(size_t)(tid + 256) * 8]); } while (0)

    #define LOADB1(k0) do { \
        _Pragma("unroll") \
        for (int i = 0; i < 4; i++) { \
            const floatx4* p = (const floatx4*)(Bg + (size_t)i * 32 * D_ + (k0)); \
            br0[i] = p[0]; br1[i] = p[1]; } } while (0)

    #define CVTWRB1(buf) do { \
        _Pragma("unroll") \
        for (int i = 0; i < 4; i++) { \
            half8 h = { (half_t)br0[i][0], (half_t)br0[i][1], (half_t)br0[i][2], (half_t)br0[i][3], \
                        (half_t)br1[i][0], (half_t)br1[i][1], (half_t)br1[i][2], (half_t)br1[i][3] }; \
            *(half8*)(&Bs[buf][bslot + i * 2048]) = h; } } while (0)

    floatx4 acc[2][4] = {};
    STAGEA1(0, 0);
    LOADB1(0);
    CVTWRB1(0);
    __syncthreads();
    int cur = 0;
    for (int k0 = 0; k0 < D_; k0 += 64) {
        bool more = (k0 + 64) < D_;
        if (more) { STAGEA1(cur ^ 1, k0 + 64); LOADB1(k0 + 64); }
        const half_t* Ab = &As[cur][0];
        const half_t* Bb = &Bs[cur][0];
        #pragma unroll
        for (int ks = 0; ks < 2; ks++) {
            half8 a[2], b[4];
            #pragma unroll
            for (int mi = 0; mi < 2; mi++)
                a[mi] = *(const half8*)(Ab + (wm + mi * 16 + l16) * 64 + ((ks * 4 + quad) ^ xm) * 8);
            #pragma unroll
            for (int ni = 0; ni < 4; ni++)
                b[ni] = *(const half8*)(Bb + (wn + ni * 16 + l16) * 64 + ((ks * 4 + quad) ^ xm) * 8);
            #pragma unroll
            for (int mi = 0; mi < 2; mi++)
                #pragma unroll
                for (int ni = 0; ni < 4; ni++)
                    acc[mi][ni] = __builtin_amdgcn_mfma_f32_16x16x32_f16(a[mi], b[ni], acc[mi][ni], 0, 0, 0);
        }
        if (more) CVTWRB1(cur ^ 1);
        __syncthreads();
        cur ^= 1;
    }
    #undef STAGEA1
    #undef LOADB1
    #undef CVTWRB1

    float bias[4];
    #pragma unroll
    for (int ni = 0; ni < 4; ni++)
        bias[ni] = b1[(size_t)e * H_ + colbase + wn + ni * 16 + l16];
    #pragma unroll
    for (int mi = 0; mi < 2; mi++) {
        #pragma unroll
        for (int r = 0; r < 4; r++) {
            int rr = wm + mi * 16 + quad * 4 + r;
            if (rr >= cnt) continue;
            size_t rowoff = (size_t)(row0 + rr) * H_;
            #pragma unroll
            for (int ni = 0; ni < 4; ni++) {
                float v = acc[mi][ni][r] + bias[ni];
                Y1[rowoff + colbase + wn + ni * 16 + l16] = (half_t)gelu_f(v);
            }
        }
    }
}

// ---------------- GEMM2 (split-K=4): Y2p[kz] = Y1 @ W2[e]^T ----------------
// same structure; A = Y1 (f16, gload_lds pre-swizzled), B = w2 (f32 reg-staged)
__global__ __launch_bounds__(256) void gemm2_kernel(
        const half_t* __restrict__ Y1, const float* __restrict__ w2,
        const int* __restrict__ tile_e, const int* __restrict__ tile_row0,
        const int* __restrict__ tile_cnt, const int* __restrict__ ntiles,
        float* __restrict__ Y2p) {
    __shared__ half_t As[2][64 * 64];
    __shared__ half_t Bs[2][128 * 64];
    int t = blockIdx.x;
    if (t >= ntiles[0]) return;
    int e = tile_e[t], row0 = tile_row0[t], cnt = tile_cnt[t];
    int colbase = blockIdx.y * 128;
    int kz = blockIdx.z;
    int kzbase = kz * 512;
    int tid = threadIdx.x;
    int wave = tid >> 6, lane = tid & 63;
    int quad = lane >> 4, l16 = lane & 15;
    int wm = (wave & 1) * 32, wn = (wave >> 1) * 64;
    int xm = l16 & 7;

    int gr = tid >> 3, gc = tid & 7;
    int gsw = gc ^ (gr & 7);

    const half_t* Ag0 = Y1 + (size_t)(row0 + gr) * H_ + kzbase + gsw * 8;
    const half_t* Ag1 = Ag0 + 32 * H_;
    const float* Bg = w2 + ((size_t)e * D_ + colbase + gr) * H_ + kzbase + gc * 8;
    int bslot = gr * 64 + gsw * 8;

    floatx4 br0[4], br1[4];

    #define STAGEA2(buf, k0) do { \
        gload_lds16(Ag0 + (k0), &As[buf][(size_t)tid * 8]); \
        gload_lds16(Ag1 + (k0), &As[buf][(size_t)(tid + 256) * 8]); } while (0)

    #define LOADB2(k0) do { \
        _Pragma("unroll") \
        for (int i = 0; i < 4; i++) { \
            const floatx4* p = (const floatx4*)(Bg + (size_t)i * 32 * H_ + (k0)); \
            br0[i] = p[0]; br1[i] = p[1]; } } while (0)

    #define CVTWRB2(buf) do { \
        _Pragma("unroll") \
        for (int i = 0; i < 4; i++) { \
            half8 h = { (half_t)br0[i][0], (half_t)br0[i][1], (half_t)br0[i][2], (half_t)br0[i][3], \
                        (half_t)br1[i][0], (half_t)br1[i][1], (half_t)br1[i][2], (half_t)br1[i][3] }; \
            *(half8*)(&Bs[buf][bslot + i * 2048]) = h; } } while (0)

    floatx4 acc[2][4] = {};
    STAGEA2(0, 0);
    LOADB2(0);
    CVTWRB2(0);
    __syncthreads();
    int cur = 0;
    for (int k0 = 0; k0 < 512; k0 += 64) {
        bool more = (k0 + 64) < 512;
        if (more) { STAGEA2(cur ^ 1, k0 + 64); LOADB2(k0 + 64); }
        const half_t* Ab = &As[cur][0];
        const half_t* Bb = &Bs[cur][0];
        #pragma unroll
        for (int ks = 0; ks < 2; ks++) {
            half8 a[2], b[4];
            #pragma unroll
            for (int mi = 0; mi < 2; mi++)
                a[mi] = *(const half8*)(Ab + (wm + mi * 16 + l16) * 64 + ((ks * 4 + quad) ^ xm) * 8);
            #pragma unroll
            for (int ni = 0; ni < 4; ni++)
                b[ni] = *(const half8*)(Bb + (wn + ni * 16 + l16) * 64 + ((ks * 4 + quad) ^ xm) * 8);
            #pragma unroll
            for (int mi = 0; mi < 2; mi++)
                #pragma unroll
                for (int ni = 0; ni < 4; ni++)
                    acc[mi][ni] = __builtin_amdgcn_mfma_f32_16x16x32_f16(a[mi], b[ni], acc[mi][ni], 0, 0, 0);
        }
        if (more) CVTWRB2(cur ^ 1);
        __syncthreads();
        cur ^= 1;
    }
    #undef STAGEA2
    #undef LOADB2
    #undef CVTWRB2

    #pragma unroll
    for (int mi = 0; mi < 2; mi++) {
        #pragma unroll
        for (int r = 0; r < 4; r++) {
            int rr = wm + mi * 16 + quad * 4 + r;
            if (rr >= cnt) continue;
            size_t rowoff = ((size_t)kz * NP + row0 + rr) * D_;
            #pragma unroll
            for (int ni = 0; ni < 4; ni++)
                Y2p[rowoff + colbase + wn + ni * 16 + l16] = acc[mi][ni][r];
        }
    }
}

// ---------------- combine + bias + LayerNorm, wave per token ----------------
__global__ __launch_bounds__(256) void final_kernel(
        const float* __restrict__ Y2p, const float* __restrict__ b2,
        const int* __restrict__ idx, const float* __restrict__ score,
        const int* __restrict__ pos_of_pair,
        const float* __restrict__ ln_w, const float* __restrict__ ln_b,
        float* __restrict__ out) {
    int n = blockIdx.x * 4 + (threadIdx.x >> 6);
    int lane = threadIdx.x & 63;
    int p0 = pos_of_pair[2 * n], p1 = pos_of_pair[2 * n + 1];
    int e0 = idx[2 * n], e1 = idx[2 * n + 1];
    float s0 = score[2 * n], s1 = score[2 * n + 1];

    const floatx4* b2r0 = (const floatx4*)(b2 + (size_t)e0 * D_);
    const floatx4* b2r1 = (const floatx4*)(b2 + (size_t)e1 * D_);
    floatx4 a_lo = b2r0[lane * 2], a_hi = b2r0[lane * 2 + 1];
    floatx4 c_lo = b2r1[lane * 2], c_hi = b2r1[lane * 2 + 1];
    #pragma unroll
    for (int kz = 0; kz < 4; kz++) {
        const floatx4* r0 = (const floatx4*)(Y2p + ((size_t)kz * NP + p0) * D_);
        const floatx4* r1 = (const floatx4*)(Y2p + ((size_t)kz * NP + p1) * D_);
        a_lo += r0[lane * 2]; a_hi += r0[lane * 2 + 1];
        c_lo += r1[lane * 2]; c_hi += r1[lane * 2 + 1];
    }
    floatx4 y_lo = s0 * a_lo + s1 * c_lo;
    floatx4 y_hi = s0 * a_hi + s1 * c_hi;

    float s = 0.0f, q = 0.0f;
    #pragma unroll
    for (int j = 0; j < 4; j++) {
        s += y_lo[j] + y_hi[j];
        q += y_lo[j] * y_lo[j] + y_hi[j] * y_hi[j];
    }
    #pragma unroll
    for (int m = 1; m < 64; m <<= 1) {
        s += __shfl_xor(s, m);
        q += __shfl_xor(q, m);
    }
    float mean = s * (1.0f / 512.0f);
    float var = q * (1.0f / 512.0f) - mean * mean;
    float inv = 1.0f / sqrtf(var + 1e-5f);

    const floatx4* wv = (const floatx4*)ln_w;
    const floatx4* bv = (const floatx4*)ln_b;
    floatx4 o_lo = (y_lo - mean) * inv * wv[lane * 2]     + bv[lane * 2];
    floatx4 o_hi = (y_hi - mean) * inv * wv[lane * 2 + 1] + bv[lane * 2 + 1];
    floatx4* op = (floatx4*)(out + (size_t)n * D_);
    op[lane * 2] = o_lo;
    op[lane * 2 + 1] = o_hi;
}

extern "C" void kernel_launch(void* const* d_in, const int* in_sizes, int n_in,
                              void* d_out, int out_size, void* d_ws, size_t ws_size,
                              hipStream_t stream) {
    const float* inp    = (const float*)d_in[0];
    const float* gate_w = (const float*)d_in[1];
    const float* gate_b = (const float*)d_in[2];
    const float* w1     = (const float*)d_in[3];
    const float* b1     = (const float*)d_in[4];
    const float* w2     = (const float*)d_in[5];
    const float* b2     = (const float*)d_in[6];
    const float* ln_w   = (const float*)d_in[7];
    const float* ln_b   = (const float*)d_in[8];
    float* out = (float*)d_out;

    char* ws = (char*)d_ws;
    size_t o = 0;
    auto carve = [&](size_t bytes) -> char* {
        char* p = ws + o;
        o += (bytes + 255) & ~(size_t)255;
        return p;
    };
    half_t* Xg  = (half_t*)carve(sizeof(half_t) * (size_t)(NP + 128) * D_);     // slack for tile overrun
    half_t* Y1  = (half_t*)carve(sizeof(half_t) * (size_t)(NP + 128) * H_);     // slack
    float*  Y2p = (float*)carve(sizeof(float) * 4 * (size_t)NP * D_);           // 16.8 MB
    float*  logits = (float*)carve(sizeof(float) * NTOK * E_);
    float*  score  = (float*)carve(sizeof(float) * NP);
    int* idx         = (int*)carve(sizeof(int) * NP);
    int* pos_of_pair = (int*)carve(sizeof(int) * NP);
    int* tile_e      = (int*)carve(sizeof(int) * MAX_TILES);
    int* tile_row0   = (int*)carve(sizeof(int) * MAX_TILES);
    int* tile_cnt    = (int*)carve(sizeof(int) * MAX_TILES);
    int* ntiles      = (int*)carve(sizeof(int) * 1);

    gate_kernel<<<NTOK / 4, 256, 0, stream>>>(inp, gate_w, gate_b, logits);
    plan_kernel<<<1, 256, 0, stream>>>(logits, score, idx, pos_of_pair,
                                       tile_e, tile_row0, tile_cnt, ntiles);
    scatter_kernel<<<NP / 4, 256, 0, stream>>>(inp, pos_of_pair, Xg);
    gemm1_kernel<<<dim3(MAX_TILES, H_ / 128), 256, 0, stream>>>(
        Xg, w1, b1, tile_e, tile_row0, tile_cnt, ntiles, Y1);
    gemm2_kernel<<<dim3(MAX_TILES, D_ / 128, 4), 256, 0, stream>>>(
        Y1, w2, tile_e, tile_row0, tile_cnt, ntiles, Y2p);
    final_kernel<<<NTOK / 4, 256, 0, stream>>>(Y2p, b2, idx, score, pos_of_pair, ln_w, ln_b, out);
}

// Round 3
// 169.454 us; speedup vs baseline: 1.0502x; 1.0502x over previous
//
#include <hip/hip_runtime.h>
#include <cstdint>
#include <cstddef>

typedef _Float16 half_t;
typedef _Float16 half8 __attribute__((ext_vector_type(8)));
typedef float floatx4 __attribute__((ext_vector_type(4)));

#define E_ 8
#define D_ 512
#define H_ 2048
#define NTOK 1024
#define NP 2048          // NTOK * top_k
#define TM 64            // GEMM M-tile (rows)
#define MAX_TILES 40     // 2048/64 + 8 experts

__device__ __forceinline__ float gelu_f(float x) {
    return 0.5f * x * (1.0f + erff(x * 0.7071067811865476f));
}

__device__ __forceinline__ half8 cvt8(floatx4 a, floatx4 b) {
    half8 h = { (half_t)a[0], (half_t)a[1], (half_t)a[2], (half_t)a[3],
                (half_t)b[0], (half_t)b[1], (half_t)b[2], (half_t)b[3] };
    return h;
}

// ---------------- gate: logits only (no atomics) ----------------
__global__ __launch_bounds__(256) void gate_kernel(
        const float* __restrict__ inp, const float* __restrict__ gate_w,
        const float* __restrict__ gate_b, float* __restrict__ logits) {
    int n = blockIdx.x * 4 + (threadIdx.x >> 6);
    int lane = threadIdx.x & 63;
    const floatx4* xr = (const floatx4*)(inp + (size_t)n * D_);
    floatx4 x0 = xr[lane * 2], x1 = xr[lane * 2 + 1];
    #pragma unroll
    for (int e = 0; e < E_; e++) {
        const floatx4* gr = (const floatx4*)(gate_w + (size_t)e * D_);
        floatx4 g0 = gr[lane * 2], g1 = gr[lane * 2 + 1];
        float p = x0[0]*g0[0] + x0[1]*g0[1] + x0[2]*g0[2] + x0[3]*g0[3]
                + x1[0]*g1[0] + x1[1]*g1[1] + x1[2]*g1[2] + x1[3]*g1[3];
        #pragma unroll
        for (int m = 1; m < 64; m <<= 1) p += __shfl_xor(p, m);
        if (lane == 0) logits[(size_t)n * E_ + e] = p + gate_b[e];
    }
}

// ---------------- plan: top2/softmax/hist/offsets/tiles/pos maps ----------------
__global__ __launch_bounds__(256) void plan_kernel(
        const float* __restrict__ logits, float* __restrict__ score,
        int* __restrict__ idx, int* __restrict__ pos_of_pair,
        int* __restrict__ tok_of_pos,
        int* __restrict__ tile_e, int* __restrict__ tile_row0,
        int* __restrict__ tile_cnt, int* __restrict__ ntiles) {
    __shared__ int cnt_s[E_], off_s[E_ + 1], cur_s[E_];
    int tid = threadIdx.x;
    if (tid < E_) { cnt_s[tid] = 0; cur_s[tid] = 0; }
    __syncthreads();
    int my_e[4][2];
    #pragma unroll
    for (int i = 0; i < 4; i++) {
        int n = tid + i * 256;
        float l[E_];
        #pragma unroll
        for (int e = 0; e < E_; e++) l[e] = logits[(size_t)n * E_ + e];
        int e0 = 0; float v0 = l[0];
        #pragma unroll
        for (int e = 1; e < E_; e++) if (l[e] > v0) { v0 = l[e]; e0 = e; }
        int e1 = -1; float v1 = -3.4e38f;
        #pragma unroll
        for (int e = 0; e < E_; e++) if (e != e0 && l[e] > v1) { v1 = l[e]; e1 = e; }
        float s1 = expf(v1 - v0);
        float den = 1.0f + s1;
        score[2 * n]     = 1.0f / den;
        score[2 * n + 1] = s1 / den;
        idx[2 * n]     = e0;
        idx[2 * n + 1] = e1;
        atomicAdd(&cnt_s[e0], 1);
        atomicAdd(&cnt_s[e1], 1);
        my_e[i][0] = e0; my_e[i][1] = e1;
    }
    __syncthreads();
    if (tid == 0) {
        int o = 0;
        #pragma unroll
        for (int e = 0; e < E_; e++) { off_s[e] = o; o += cnt_s[e]; }
        off_s[E_] = o;
        int t = 0;
        for (int e = 0; e < E_; e++) {
            int c = cnt_s[e];
            int nt = (c + TM - 1) / TM;
            for (int i = 0; i < nt; i++) {
                tile_e[t] = e;
                tile_row0[t] = off_s[e] + i * TM;
                int rem = c - i * TM;
                tile_cnt[t] = rem < TM ? rem : TM;
                t++;
            }
        }
        ntiles[0] = t;
    }
    __syncthreads();
    #pragma unroll
    for (int i = 0; i < 4; i++) {
        #pragma unroll
        for (int k = 0; k < 2; k++) {
            int p = (tid + i * 256) * 2 + k;
            int e = my_e[i][k];
            int r = atomicAdd(&cur_s[e], 1);
            int pos = off_s[e] + r;
            pos_of_pair[p] = pos;
            tok_of_pos[pos] = p >> 1;
        }
    }
}

// ---------------- GEMM1: Y1 = gelu(inp[tok] @ W1[e]^T + b1[e]) ----------------
// 64x64 tile, BK=64, double-buffered LDS (32 KB -> 5 blocks/CU), XOR swizzle on
// both write and read, A gathered from inp fp32 via tok_of_pos, B from w1 fp32.
__global__ __launch_bounds__(256) void gemm1_kernel(
        const float* __restrict__ inp, const int* __restrict__ tok_of_pos,
        const float* __restrict__ w1, const float* __restrict__ b1,
        const int* __restrict__ tile_e, const int* __restrict__ tile_row0,
        const int* __restrict__ tile_cnt, const int* __restrict__ ntiles,
        half_t* __restrict__ Y1) {
    __shared__ half_t As[2][64 * 64];   // 2 x 8 KB
    __shared__ half_t Bs[2][64 * 64];   // 2 x 8 KB
    // XCD-chunked remap: contiguous work chunk per XCD -> B panel fits L2
    int flat = blockIdx.x + gridDim.x * blockIdx.y;
    int per = (gridDim.x * gridDim.y) >> 3;
    int f2 = (flat & 7) * per + (flat >> 3);
    int t = f2 % MAX_TILES;
    int cb = f2 / MAX_TILES;
    if (t >= ntiles[0]) return;
    int e = tile_e[t], row0 = tile_row0[t], cnt = tile_cnt[t];
    int colbase = cb * 64;
    int tid = threadIdx.x;
    int wave = tid >> 6, lane = tid & 63;
    int quad = lane >> 4, l16 = lane & 15;
    int wm = (wave & 1) * 32, wn = (wave >> 1) * 32;
    int xm = l16 & 7;

    // two granules per thread: g0 = tid (rows 0..31), g1 = tid+256 (rows 32..63)
    int gr0 = tid >> 3, gr1 = gr0 + 32, gc = tid & 7;
    int sw0 = gc ^ (gr0 & 7), sw1 = gc ^ (gr1 & 7);
    int ar0 = row0 + gr0; if (ar0 > NP - 1) ar0 = NP - 1;
    int ar1 = row0 + gr1; if (ar1 > NP - 1) ar1 = NP - 1;
    int tok0 = tok_of_pos[ar0];
    int tok1 = tok_of_pos[ar1];
    const floatx4* Ag0 = (const floatx4*)(inp + (size_t)tok0 * D_) + gc * 2;
    const floatx4* Ag1 = (const floatx4*)(inp + (size_t)tok1 * D_) + gc * 2;
    const floatx4* Bg0 = (const floatx4*)(w1 + ((size_t)e * H_ + colbase + gr0) * D_) + gc * 2;
    const floatx4* Bg1 = (const floatx4*)(w1 + ((size_t)e * H_ + colbase + gr1) * D_) + gc * 2;
    int sa0 = gr0 * 64 + sw0 * 8, sa1 = gr1 * 64 + sw1 * 8;

    floatx4 ra0a, ra0b, ra1a, ra1b, rb0a, rb0b, rb1a, rb1b;
    #define LOAD1(kq) do { \
        ra0a = Ag0[kq]; ra0b = Ag0[(kq) + 1]; \
        ra1a = Ag1[kq]; ra1b = Ag1[(kq) + 1]; \
        rb0a = Bg0[kq]; rb0b = Bg0[(kq) + 1]; \
        rb1a = Bg1[kq]; rb1b = Bg1[(kq) + 1]; } while (0)
    #define CVW1(buf) do { \
        *(half8*)(&As[buf][sa0]) = cvt8(ra0a, ra0b); \
        *(half8*)(&As[buf][sa1]) = cvt8(ra1a, ra1b); \
        *(half8*)(&Bs[buf][sa0]) = cvt8(rb0a, rb0b); \
        *(half8*)(&Bs[buf][sa1]) = cvt8(rb1a, rb1b); } while (0)

    floatx4 acc[2][2] = {};
    LOAD1(0);
    CVW1(0);
    __syncthreads();
    int cur = 0;
    for (int k0 = 0; k0 < D_; k0 += 64) {
        bool more = (k0 + 64) < D_;
        if (more) LOAD1((k0 + 64) >> 2);
        const half_t* Ab = &As[cur][0];
        const half_t* Bb = &Bs[cur][0];
        #pragma unroll
        for (int ks = 0; ks < 2; ks++) {
            half8 a[2], b[2];
            #pragma unroll
            for (int mi = 0; mi < 2; mi++)
                a[mi] = *(const half8*)(Ab + (wm + mi * 16 + l16) * 64 + ((ks * 4 + quad) ^ xm) * 8);
            #pragma unroll
            for (int ni = 0; ni < 2; ni++)
                b[ni] = *(const half8*)(Bb + (wn + ni * 16 + l16) * 64 + ((ks * 4 + quad) ^ xm) * 8);
            #pragma unroll
            for (int mi = 0; mi < 2; mi++)
                #pragma unroll
                for (int ni = 0; ni < 2; ni++)
                    acc[mi][ni] = __builtin_amdgcn_mfma_f32_16x16x32_f16(a[mi], b[ni], acc[mi][ni], 0, 0, 0);
        }
        if (more) CVW1(cur ^ 1);
        __syncthreads();
        cur ^= 1;
    }
    #undef LOAD1
    #undef CVW1

    float bias[2];
    #pragma unroll
    for (int ni = 0; ni < 2; ni++)
        bias[ni] = b1[(size_t)e * H_ + colbase + wn + ni * 16 + l16];
    #pragma unroll
    for (int mi = 0; mi < 2; mi++) {
        #pragma unroll
        for (int r = 0; r < 4; r++) {
            int rr = wm + mi * 16 + quad * 4 + r;
            if (rr >= cnt) continue;
            size_t rowoff = (size_t)(row0 + rr) * H_;
            #pragma unroll
            for (int ni = 0; ni < 2; ni++) {
                float v = acc[mi][ni][r] + bias[ni];
                Y1[rowoff + colbase + wn + ni * 16 + l16] = (half_t)gelu_f(v);
            }
        }
    }
}

// ---------------- GEMM2 (split-K=4): Y2p[kz] = Y1 @ W2[e]^T ----------------
// 64x64 tile, BK=64, same swizzled double-buffer; A = Y1 f16, B = w2 fp32.
__global__ __launch_bounds__(256) void gemm2_kernel(
        const half_t* __restrict__ Y1, const float* __restrict__ w2,
        const int* __restrict__ tile_e, const int* __restrict__ tile_row0,
        const int* __restrict__ tile_cnt, const int* __restrict__ ntiles,
        float* __restrict__ Y2p) {
    __shared__ half_t As[2][64 * 64];
    __shared__ half_t Bs[2][64 * 64];
    int flat = blockIdx.x + gridDim.x * (blockIdx.y + gridDim.y * blockIdx.z);
    int per = (gridDim.x * gridDim.y * gridDim.z) >> 3;
    int f2 = (flat & 7) * per + (flat >> 3);
    int t = f2 % MAX_TILES;
    int rest = f2 / MAX_TILES;
    int cb = rest & 7;          // D_/64 = 8
    int kz = rest >> 3;         // 4
    if (t >= ntiles[0]) return;
    int e = tile_e[t], row0 = tile_row0[t], cnt = tile_cnt[t];
    int colbase = cb * 64;
    int kzbase = kz * 512;
    int tid = threadIdx.x;
    int wave = tid >> 6, lane = tid & 63;
    int quad = lane >> 4, l16 = lane & 15;
    int wm = (wave & 1) * 32, wn = (wave >> 1) * 32;
    int xm = l16 & 7;

    int gr0 = tid >> 3, gr1 = gr0 + 32, gc = tid & 7;
    int sw0 = gc ^ (gr0 & 7), sw1 = gc ^ (gr1 & 7);
    const half8* Ag0 = (const half8*)(Y1 + (size_t)(row0 + gr0) * H_ + kzbase) + gc;
    const half8* Ag1 = (const half8*)(Y1 + (size_t)(row0 + gr1) * H_ + kzbase) + gc;
    const floatx4* Bg0 = (const floatx4*)(w2 + ((size_t)e * D_ + colbase + gr0) * H_ + kzbase) + gc * 2;
    const floatx4* Bg1 = (const floatx4*)(w2 + ((size_t)e * D_ + colbase + gr1) * H_ + kzbase) + gc * 2;
    int sa0 = gr0 * 64 + sw0 * 8, sa1 = gr1 * 64 + sw1 * 8;

    half8 ha0, ha1;
    floatx4 rb0a, rb0b, rb1a, rb1b;
    #define LOAD2(k0) do { \
        ha0 = Ag0[(k0) >> 3]; ha1 = Ag1[(k0) >> 3]; \
        rb0a = Bg0[(k0) >> 2]; rb0b = Bg0[((k0) >> 2) + 1]; \
        rb1a = Bg1[(k0) >> 2]; rb1b = Bg1[((k0) >> 2) + 1]; } while (0)
    #define CVW2(buf) do { \
        *(half8*)(&As[buf][sa0]) = ha0; \
        *(half8*)(&As[buf][sa1]) = ha1; \
        *(half8*)(&Bs[buf][sa0]) = cvt8(rb0a, rb0b); \
        *(half8*)(&Bs[buf][sa1]) = cvt8(rb1a, rb1b); } while (0)

    floatx4 acc[2][2] = {};
    LOAD2(0);
    CVW2(0);
    __syncthreads();
    int cur = 0;
    for (int k0 = 0; k0 < 512; k0 += 64) {
        bool more = (k0 + 64) < 512;
        if (more) LOAD2(k0 + 64);
        const half_t* Ab = &As[cur][0];
        const half_t* Bb = &Bs[cur][0];
        #pragma unroll
        for (int ks = 0; ks < 2; ks++) {
            half8 a[2], b[2];
            #pragma unroll
            for (int mi = 0; mi < 2; mi++)
                a[mi] = *(const half8*)(Ab + (wm + mi * 16 + l16) * 64 + ((ks * 4 + quad) ^ xm) * 8);
            #pragma unroll
            for (int ni = 0; ni < 2; ni++)
                b[ni] = *(const half8*)(Bb + (wn + ni * 16 + l16) * 64 + ((ks * 4 + quad) ^ xm) * 8);
            #pragma unroll
            for (int mi = 0; mi < 2; mi++)
                #pragma unroll
                for (int ni = 0; ni < 2; ni++)
                    acc[mi][ni] = __builtin_amdgcn_mfma_f32_16x16x32_f16(a[mi], b[ni], acc[mi][ni], 0, 0, 0);
        }
        if (more) CVW2(cur ^ 1);
        __syncthreads();
        cur ^= 1;
    }
    #undef LOAD2
    #undef CVW2

    #pragma unroll
    for (int mi = 0; mi < 2; mi++) {
        #pragma unroll
        for (int r = 0; r < 4; r++) {
            int rr = wm + mi * 16 + quad * 4 + r;
            if (rr >= cnt) continue;
            size_t rowoff = ((size_t)kz * NP + row0 + rr) * D_;
            #pragma unroll
            for (int ni = 0; ni < 2; ni++)
                Y2p[rowoff + colbase + wn + ni * 16 + l16] = acc[mi][ni][r];
        }
    }
}

// ---------------- combine + bias + LayerNorm, wave per token ----------------
__global__ __launch_bounds__(256) void final_kernel(
        const float* __restrict__ Y2p, const float* __restrict__ b2,
        const int* __restrict__ idx, const float* __restrict__ score,
        const int* __restrict__ pos_of_pair,
        const float* __restrict__ ln_w, const float* __restrict__ ln_b,
        float* __restrict__ out) {
    int n = blockIdx.x * 4 + (threadIdx.x >> 6);
    int lane = threadIdx.x & 63;
    int p0 = pos_of_pair[2 * n], p1 = pos_of_pair[2 * n + 1];
    int e0 = idx[2 * n], e1 = idx[2 * n + 1];
    float s0 = score[2 * n], s1 = score[2 * n + 1];

    const floatx4* b2r0 = (const floatx4*)(b2 + (size_t)e0 * D_);
    const floatx4* b2r1 = (const floatx4*)(b2 + (size_t)e1 * D_);
    floatx4 a_lo = b2r0[lane * 2], a_hi = b2r0[lane * 2 + 1];
    floatx4 c_lo = b2r1[lane * 2], c_hi = b2r1[lane * 2 + 1];
    #pragma unroll
    for (int kz = 0; kz < 4; kz++) {
        const floatx4* r0 = (const floatx4*)(Y2p + ((size_t)kz * NP + p0) * D_);
        const floatx4* r1 = (const floatx4*)(Y2p + ((size_t)kz * NP + p1) * D_);
        a_lo += r0[lane * 2]; a_hi += r0[lane * 2 + 1];
        c_lo += r1[lane * 2]; c_hi += r1[lane * 2 + 1];
    }
    floatx4 y_lo = s0 * a_lo + s1 * c_lo;
    floatx4 y_hi = s0 * a_hi + s1 * c_hi;

    float s = 0.0f, q = 0.0f;
    #pragma unroll
    for (int j = 0; j < 4; j++) {
        s += y_lo[j] + y_hi[j];
        q += y_lo[j] * y_lo[j] + y_hi[j] * y_hi[j];
    }
    #pragma unroll
    for (int m = 1; m < 64; m <<= 1) {
        s += __shfl_xor(s, m);
        q += __shfl_xor(q, m);
    }
    float mean = s * (1.0f / 512.0f);
    float var = q * (1.0f / 512.0f) - mean * mean;
    float inv = 1.0f / sqrtf(var + 1e-5f);

    const floatx4* wv = (const floatx4*)ln_w;
    const floatx4* bv = (const floatx4*)ln_b;
    floatx4 o_lo = (y_lo - mean) * inv * wv[lane * 2]     + bv[lane * 2];
    floatx4 o_hi = (y_hi - mean) * inv * wv[lane * 2 + 1] + bv[lane * 2 + 1];
    floatx4* op = (floatx4*)(out + (size_t)n * D_);
    op[lane * 2] = o_lo;
    op[lane * 2 + 1] = o_hi;
}

extern "C" void kernel_launch(void* const* d_in, const int* in_sizes, int n_in,
                              void* d_out, int out_size, void* d_ws, size_t ws_size,
                              hipStream_t stream) {
    const float* inp    = (const float*)d_in[0];
    const float* gate_w = (const float*)d_in[1];
    const float* gate_b = (const float*)d_in[2];
    const float* w1     = (const float*)d_in[3];
    const float* b1     = (const float*)d_in[4];
    const float* w2     = (const float*)d_in[5];
    const float* b2     = (const float*)d_in[6];
    const float* ln_w   = (const float*)d_in[7];
    const float* ln_b   = (const float*)d_in[8];
    float* out = (float*)d_out;

    char* ws = (char*)d_ws;
    size_t o = 0;
    auto carve = [&](size_t bytes) -> char* {
        char* p = ws + o;
        o += (bytes + 255) & ~(size_t)255;
        return p;
    };
    half_t* Y1  = (half_t*)carve(sizeof(half_t) * (size_t)(NP + 128) * H_);     // slack rows for tile overrun
    float*  Y2p = (float*)carve(sizeof(float) * 4 * (size_t)NP * D_);           // 16.8 MB
    float*  logits = (float*)carve(sizeof(float) * NTOK * E_);
    float*  score  = (float*)carve(sizeof(float) * NP);
    int* idx         = (int*)carve(sizeof(int) * NP);
    int* pos_of_pair = (int*)carve(sizeof(int) * NP);
    int* tok_of_pos  = (int*)carve(sizeof(int) * NP);
    int* tile_e      = (int*)carve(sizeof(int) * MAX_TILES);
    int* tile_row0   = (int*)carve(sizeof(int) * MAX_TILES);
    int* tile_cnt    = (int*)carve(sizeof(int) * MAX_TILES);
    int* ntiles      = (int*)carve(sizeof(int) * 1);

    gate_kernel<<<NTOK / 4, 256, 0, stream>>>(inp, gate_w, gate_b, logits);
    plan_kernel<<<1, 256, 0, stream>>>(logits, score, idx, pos_of_pair, tok_of_pos,
                                       tile_e, tile_row0, tile_cnt, ntiles);
    gemm1_kernel<<<dim3(MAX_TILES, H_ / 64), 256, 0, stream>>>(
        inp, tok_of_pos, w1, b1, tile_e, tile_row0, tile_cnt, ntiles, Y1);
    gemm2_kernel<<<dim3(MAX_TILES, D_ / 64, 4), 256, 0, stream>>>(
        Y1, w2, tile_e, tile_row0, tile_cnt, ntiles, Y2p);
    final_kernel<<<NTOK / 4, 256, 0, stream>>>(Y2p, b2, idx, score, pos_of_pair, ln_w, ln_b, out);
}